// Round 1
// 1400.207 us; speedup vs baseline: 1.0880x; 1.0880x over previous
//
#include <hip/hip_runtime.h>
#include <stdint.h>

typedef uint32_t u32;

constexpr int Bb = 4, Ww = 1024, Vv = 50257, Dd = 256;
constexpr int ROWS = Bb * Ww;   // 4096
constexpr int TPB  = 256;
constexpr int NG    = Vv / 4;          // 12564 full float4 groups
constexpr int KFULL = NG / TPB;        // 49 full iterations for all threads
constexpr int KPAIR = KFULL / 2;       // 24 double-iterations (k=0..47)
constexpr int GREM  = NG - KFULL*TPB;  // 20 leftover groups (+1 scalar elem 50256)

struct TF { u32 a, b; };

__host__ __device__ constexpr TF tf2x32(u32 k0, u32 k1, u32 c0, u32 c1) {
  u32 ks2 = k0 ^ k1 ^ 0x1BD11BDAu;
  u32 x0 = c0 + k0;
  u32 x1 = c1 + k1;
#define TFR(r) { x0 += x1; x1 = (x1 << (r)) | (x1 >> (32 - (r))); x1 ^= x0; }
  TFR(13) TFR(15) TFR(26) TFR(6)
  x0 += k1;  x1 += ks2 + 1u;
  TFR(17) TFR(29) TFR(16) TFR(24)
  x0 += ks2; x1 += k0 + 2u;
  TFR(13) TFR(15) TFR(26) TFR(6)
  x0 += k0;  x1 += k1 + 3u;
  TFR(17) TFR(29) TFR(16) TFR(24)
  x0 += k1;  x1 += ks2 + 4u;
  TFR(13) TFR(15) TFR(26) TFR(6)
  x0 += ks2; x1 += k0 + 5u;
#undef TFR
  return {x0, x1};
}

// partitionable split: keys[i] = fold-like threefry(key,(0,i)) -> (out0,out1)
constexpr TF KS_ = tf2x32(0u, 42u, 0u, 0u);  // k_samp
constexpr TF KA_ = tf2x32(0u, 42u, 0u, 1u);  // k_ans
constexpr u32 SK0 = KS_.a, SK1 = KS_.b, AK0 = KA_.a, AK1 = KA_.b;
constexpr u32 SKS2 = SK0 ^ SK1 ^ 0x1BD11BDAu;

__device__ __forceinline__ u32 tf_bits(u32 k0, u32 k1, u32 n) {
  TF r = tf2x32(k0, k1, 0u, n);
  return r.a ^ r.b;
}

// 4-wide interleaved threefry (tail path): counter lo = n0+j, fold = x0^x1.
__device__ __forceinline__ void tf_bits4(u32 x1base, u32 out[4]) {
  u32 x0[4], x1[4];
#pragma unroll
  for (int j = 0; j < 4; j++) { x0[j] = SK0; x1[j] = x1base + (u32)j; }
#define TFR4(r) \
  _Pragma("unroll") for (int j = 0; j < 4; j++) { \
    x0[j] += x1[j]; x1[j] = (x1[j] << (r)) | (x1[j] >> (32 - (r))); x1[j] ^= x0[j]; }
#define INJ4(ka, kb) \
  _Pragma("unroll") for (int j = 0; j < 4; j++) { x0[j] += (ka); x1[j] += (kb); }
  TFR4(13) TFR4(15) TFR4(26) TFR4(6)
  INJ4(SK1, SKS2 + 1u)
  TFR4(17) TFR4(29) TFR4(16) TFR4(24)
  INJ4(SKS2, SK0 + 2u)
  TFR4(13) TFR4(15) TFR4(26) TFR4(6)
  INJ4(SK0, SK1 + 3u)
  TFR4(17) TFR4(29) TFR4(16) TFR4(24)
  INJ4(SK1, SKS2 + 4u)
  TFR4(13) TFR4(15) TFR4(26) TFR4(6)
  INJ4(SKS2, SK0 + 5u)
#undef TFR4
#undef INJ4
#pragma unroll
  for (int j = 0; j < 4; j++) out[j] = x0[j] ^ x1[j];
}

// 8-wide interleaved threefry: two float4 groups (bases b0, b1 = counter-lo with
// key pre-folded). 8 independent chains -> double the ILP of tf_bits4.
__device__ __forceinline__ void tf_bits8(u32 b0, u32 b1, u32 out[8]) {
  u32 x0[8], x1[8];
#pragma unroll
  for (int j = 0; j < 4; j++) {
    x0[j]     = SK0; x1[j]     = b0 + (u32)j;
    x0[j + 4] = SK0; x1[j + 4] = b1 + (u32)j;
  }
#define TFR8(r) \
  _Pragma("unroll") for (int j = 0; j < 8; j++) { \
    x0[j] += x1[j]; x1[j] = (x1[j] << (r)) | (x1[j] >> (32 - (r))); x1[j] ^= x0[j]; }
#define INJ8(ka, kb) \
  _Pragma("unroll") for (int j = 0; j < 8; j++) { x0[j] += (ka); x1[j] += (kb); }
  TFR8(13) TFR8(15) TFR8(26) TFR8(6)
  INJ8(SK1, SKS2 + 1u)
  TFR8(17) TFR8(29) TFR8(16) TFR8(24)
  INJ8(SKS2, SK0 + 2u)
  TFR8(13) TFR8(15) TFR8(26) TFR8(6)
  INJ8(SK0, SK1 + 3u)
  TFR8(17) TFR8(29) TFR8(16) TFR8(24)
  INJ8(SK1, SKS2 + 4u)
  TFR8(13) TFR8(15) TFR8(26) TFR8(6)
  INJ8(SKS2, SK0 + 5u)
#undef TFR8
#undef INJ8
#pragma unroll
  for (int j = 0; j < 8; j++) out[j] = x0[j] ^ x1[j];
}

__device__ __forceinline__ float gumbel_from_bits(u32 bits) {
  // identical formula to the bit-exact-verified version
  u32 m = bits >> 9;
  float u = (float)m * 0x1p-23f;
  if (m == 0u) u = 1.1754943508222875e-38f;
  float nl = -__logf(u);
  return -__logf(nl);
}

// branchless sorted-4 insert (desc); strict '>' keeps earlier (lower) index on tie
__device__ __forceinline__ void ins4(float& v0, float& v1, float& v2, float& v3,
                                     u32& j0, u32& j1, u32& j2, u32& j3,
                                     float t, u32 idx) {
  bool c0 = t > v0;
  float f1 = c0 ? v0 : t;  u32 fi1 = c0 ? j0 : idx;
  v0 = c0 ? t : v0;        j0 = c0 ? idx : j0;
  bool c1 = f1 > v1;
  float f2 = c1 ? v1 : f1; u32 fi2 = c1 ? j1 : fi1;
  v1 = c1 ? f1 : v1;       j1 = c1 ? fi1 : j1;
  bool c2 = f2 > v2;
  float f3 = c2 ? v2 : f2; u32 fi3 = c2 ? j2 : fi2;
  v2 = c2 ? f2 : v2;       j2 = c2 ? fi2 : j2;
  bool c3 = f3 > v3;
  v3 = c3 ? f3 : v3;       j3 = c3 ? fi3 : j3;
}

__global__ __launch_bounds__(TPB, 6) void fused_kernel(
    const float* __restrict__ datax,    // [ROWS, D]
    const float* __restrict__ logits,   // [ROWS, V]
    const int*   __restrict__ labels,   // [ROWS]
    const float* __restrict__ pt_emb,   // [V, D]
    const float* __restrict__ pt_bias,  // [V]
    const float* __restrict__ imask,    // [ROWS]
    float* __restrict__ acc)            // [2]: {sum(ce*w), sum(w)}
{
  const int row = blockIdx.x;
  const int tid = threadIdx.x;
  // force lbl into an SGPR so label-window checks are scalar branches
  const u32 lbl = (u32)__builtin_amdgcn_readfirstlane(labels[row]);
  const float* xrow = logits + (size_t)row * Vv;
  const float4* xv4 = (const float4*)xrow;
  const u32 nb = (u32)row * (u32)Vv + SK1;   // counter-lo base with key pre-folded

  float v0 = -INFINITY, v1 = -INFINITY, v2 = -INFINITY, v3 = -INFINITY;
  u32 j0 = 0xFFFFFFFFu, j1 = 0xFFFFFFFFu, j2 = 0xFFFFFFFFu, j3 = 0xFFFFFFFFu;

  int g = tid;
  for (int k2 = 0; k2 < KPAIR; k2++, g += 2 * TPB) {
    float4 xa = xv4[g];
    float4 xb = xv4[g + TPB];
    u32 o[8];
    tf_bits8(nb + 4u * (u32)g, nb + 4u * (u32)(g + TPB), o);
    u32 i0 = 4u * (u32)g;
    u32 i1 = i0 + 4u * (u32)TPB;
    float t0 = xa.x + gumbel_from_bits(o[0]);
    float t1 = xa.y + gumbel_from_bits(o[1]);
    float t2 = xa.z + gumbel_from_bits(o[2]);
    float t3 = xa.w + gumbel_from_bits(o[3]);
    float t4 = xb.x + gumbel_from_bits(o[4]);
    float t5 = xb.y + gumbel_from_bits(o[5]);
    float t6 = xb.z + gumbel_from_bits(o[6]);
    float t7 = xb.w + gumbel_from_bits(o[7]);
    // scalar-guarded label masking: the wave's 64 lanes cover a contiguous
    // 256-element window; label lands in it ~once per row -> s_cbranch skip.
    u32 f0 = (u32)__builtin_amdgcn_readfirstlane((int)i0);
    if (__builtin_expect(lbl - f0 < 256u, 0)) {
      t0 = (i0 + 0u == lbl) ? -INFINITY : t0;
      t1 = (i0 + 1u == lbl) ? -INFINITY : t1;
      t2 = (i0 + 2u == lbl) ? -INFINITY : t2;
      t3 = (i0 + 3u == lbl) ? -INFINITY : t3;
    }
    if (__builtin_expect(lbl - (f0 + 1024u) < 256u, 0)) {
      t4 = (i1 + 0u == lbl) ? -INFINITY : t4;
      t5 = (i1 + 1u == lbl) ? -INFINITY : t5;
      t6 = (i1 + 2u == lbl) ? -INFINITY : t6;
      t7 = (i1 + 3u == lbl) ? -INFINITY : t7;
    }
    ins4(v0,v1,v2,v3, j0,j1,j2,j3, t0, i0 + 0u);
    ins4(v0,v1,v2,v3, j0,j1,j2,j3, t1, i0 + 1u);
    ins4(v0,v1,v2,v3, j0,j1,j2,j3, t2, i0 + 2u);
    ins4(v0,v1,v2,v3, j0,j1,j2,j3, t3, i0 + 3u);
    ins4(v0,v1,v2,v3, j0,j1,j2,j3, t4, i1 + 0u);
    ins4(v0,v1,v2,v3, j0,j1,j2,j3, t5, i1 + 1u);
    ins4(v0,v1,v2,v3, j0,j1,j2,j3, t6, i1 + 2u);
    ins4(v0,v1,v2,v3, j0,j1,j2,j3, t7, i1 + 3u);
  }
  // k = 48: last full-coverage group (KFULL is odd)
  {
    float4 xv = xv4[g];
    u32 o[4];
    tf_bits4(nb + 4u * (u32)g, o);
    u32 i0 = 4u * (u32)g;
    float t0 = xv.x + gumbel_from_bits(o[0]);
    float t1 = xv.y + gumbel_from_bits(o[1]);
    float t2 = xv.z + gumbel_from_bits(o[2]);
    float t3 = xv.w + gumbel_from_bits(o[3]);
    t0 = (i0 + 0u == lbl) ? -INFINITY : t0;
    t1 = (i0 + 1u == lbl) ? -INFINITY : t1;
    t2 = (i0 + 2u == lbl) ? -INFINITY : t2;
    t3 = (i0 + 3u == lbl) ? -INFINITY : t3;
    ins4(v0,v1,v2,v3, j0,j1,j2,j3, t0, i0 + 0u);
    ins4(v0,v1,v2,v3, j0,j1,j2,j3, t1, i0 + 1u);
    ins4(v0,v1,v2,v3, j0,j1,j2,j3, t2, i0 + 2u);
    ins4(v0,v1,v2,v3, j0,j1,j2,j3, t3, i0 + 3u);
  }
  // tail: 20 leftover float4 groups + 1 scalar element (50256)
  if (tid < GREM) {
    int gg = KFULL * TPB + tid;
    float4 xv = xv4[gg];
    u32 o[4];
    tf_bits4(nb + 4u * (u32)gg, o);
    u32 i0 = 4u * (u32)gg;
    float t0 = xv.x + gumbel_from_bits(o[0]);
    float t1 = xv.y + gumbel_from_bits(o[1]);
    float t2 = xv.z + gumbel_from_bits(o[2]);
    float t3 = xv.w + gumbel_from_bits(o[3]);
    t0 = (i0 + 0u == lbl) ? -INFINITY : t0;
    t1 = (i0 + 1u == lbl) ? -INFINITY : t1;
    t2 = (i0 + 2u == lbl) ? -INFINITY : t2;
    t3 = (i0 + 3u == lbl) ? -INFINITY : t3;
    ins4(v0,v1,v2,v3, j0,j1,j2,j3, t0, i0 + 0u);
    ins4(v0,v1,v2,v3, j0,j1,j2,j3, t1, i0 + 1u);
    ins4(v0,v1,v2,v3, j0,j1,j2,j3, t2, i0 + 2u);
    ins4(v0,v1,v2,v3, j0,j1,j2,j3, t3, i0 + 3u);
  }
  if (tid == GREM) {
    u32 iL = (u32)(Vv - 1);
    float x = xrow[Vv - 1];
    float t = x + gumbel_from_bits(tf_bits(SK0, SK1, nb - SK1 + iL));
    t = (iL == lbl) ? -INFINITY : t;
    ins4(v0,v1,v2,v3, j0,j1,j2,j3, t, iL);
  }

  // ---- LDS tree merge of sorted-4 lists (desc by value, ties -> lower index) ----
  __shared__ float sv[TPB][4];
  __shared__ u32   si[TPB][4];
  sv[tid][0]=v0; sv[tid][1]=v1; sv[tid][2]=v2; sv[tid][3]=v3;
  si[tid][0]=j0; si[tid][1]=j1; si[tid][2]=j2; si[tid][3]=j3;

  for (int off = TPB / 2; off > 0; off >>= 1) {
    __syncthreads();
    if (tid < off) {
      float av[4], bv[4], mv[4];
      u32   ai[4], bi[4], mi[4];
      #pragma unroll
      for (int k = 0; k < 4; k++) { av[k]=sv[tid][k]; ai[k]=si[tid][k];
                                    bv[k]=sv[tid+off][k]; bi[k]=si[tid+off][k]; }
      int pa = 0, pb = 0;
      #pragma unroll
      for (int k = 0; k < 4; k++) {
        bool takeA = (av[pa] > bv[pb]) ||
                     (av[pa] == bv[pb] && ai[pa] < bi[pb]);
        mv[k] = takeA ? av[pa] : bv[pb];
        mi[k] = takeA ? ai[pa] : bi[pb];
        if (takeA) pa++; else pb++;
      }
      #pragma unroll
      for (int k = 0; k < 4; k++) { sv[tid][k]=mv[k]; si[tid][k]=mi[k]; }
    }
  }
  __syncthreads();

  // ---- answer draw + mctask ----
  __shared__ int mct[4];
  __shared__ int s_ans;
  if (tid == 0) {
    u32 abits = tf_bits(AK0, AK1, (u32)row);  // randint span 4 -> bits & 3
    int ans = (int)(abits & 3u);
    s_ans = ans;
    #pragma unroll
    for (int c = 0; c < 4; c++) mct[c] = (c == ans) ? (int)lbl : (int)si[0][c];
  }
  __syncthreads();

  // ---- 4 x (256-dot) + bias, one wave per candidate ----
  int c = tid >> 6, lane = tid & 63;
  int id = mct[c];
  float4 ev = ((const float4*)(pt_emb + (size_t)id  * Dd))[lane];
  float4 dv = ((const float4*)(datax  + (size_t)row * Dd))[lane];
  float p = ev.x*dv.x + ev.y*dv.y + ev.z*dv.z + ev.w*dv.w;
  #pragma unroll
  for (int o = 32; o > 0; o >>= 1) p += __shfl_down(p, o, 64);

  __shared__ float sc[4];
  if (lane == 0) sc[c] = p + pt_bias[id];
  __syncthreads();

  if (tid == 0) {
    float m = fmaxf(fmaxf(sc[0], sc[1]), fmaxf(sc[2], sc[3]));
    float s = expf(sc[0]-m) + expf(sc[1]-m) + expf(sc[2]-m) + expf(sc[3]-m);
    float lse = m + logf(s);
    float ce = lse - sc[s_ans];
    float wm = 1.0f - imask[row];
    atomicAdd(&acc[0], ce * wm);
    atomicAdd(&acc[1], wm);
  }
}

__global__ void finalize_kernel(const float* __restrict__ acc,
                                float* __restrict__ out) {
  if (threadIdx.x == 0) out[0] = acc[0] / acc[1];
}

extern "C" void kernel_launch(void* const* d_in, const int* in_sizes, int n_in,
                              void* d_out, int out_size, void* d_ws, size_t ws_size,
                              hipStream_t stream) {
  const float* datax   = (const float*)d_in[0];
  const float* logits  = (const float*)d_in[1];
  const int*   labels  = (const int*)  d_in[2];
  const float* pt_emb  = (const float*)d_in[3];
  const float* pt_bias = (const float*)d_in[4];
  const float* imask   = (const float*)d_in[5];
  float* acc = (float*)d_ws;

  hipMemsetAsync(acc, 0, 2 * sizeof(float), stream);
  fused_kernel<<<ROWS, TPB, 0, stream>>>(datax, logits, labels, pt_emb,
                                         pt_bias, imask, acc);
  finalize_kernel<<<1, 64, 0, stream>>>(acc, (float*)d_out);
}